// Round 4
// baseline (421.176 us; speedup 1.0000x reference)
//
#include <hip/hip_runtime.h>
#include <hip/hip_bf16.h>

#define N_NODES  50000
#define N_EDGES  300000
#define IN_FEATS 1433
#define HIDDEN   16
#define OUT_F    7
#define KPAD     1472   // 23*64, zero-padded K extent for W1 in LDS
#define WROW     9      // dwords per W1 row in LDS (stride 9 -> 2-way alias = free)
#define GRID     512    // 2 blocks/CU guaranteed (LDS allows 3; VGPR<=256) -> co-resident

__device__ __forceinline__ unsigned short f2bf(float f) {
    unsigned int x = __float_as_uint(f);
    unsigned int r = x + 0x7fffu + ((x >> 16) & 1u);   // RNE
    return (unsigned short)(r >> 16);
}

// Hand-rolled grid barrier: monotonic counter, per-phase target = phase*GRID.
// Release fence before arrival; agent-scope acquire spin; post-fence by ALL
// threads so every CU/XCD invalidates stale L1/L2 (ws reused across replays).
__device__ __forceinline__ void grid_barrier(unsigned int* bar, unsigned int target) {
    __syncthreads();
    if (threadIdx.x == 0) {
        __threadfence();   // device-scope release of this block's writes
        __hip_atomic_fetch_add(bar, 1u, __ATOMIC_ACQ_REL, __HIP_MEMORY_SCOPE_AGENT);
        while (__hip_atomic_load(bar, __ATOMIC_ACQUIRE, __HIP_MEMORY_SCOPE_AGENT) < target) {
            __builtin_amdgcn_s_sleep(8);
        }
    }
    __syncthreads();
    __threadfence();       // device-scope acquire for every thread
}

// One fused kernel, plain launch (no cooperative API):
//   P1: H = F @ W1 (bf16 W in LDS); aggbuf = H + b1
//   P2: aggbuf[dst] += H[src]
//   P3: x = relu(aggbuf); G = x@W2 (G aliases H); out = G + b2
//   P4: out[dst] += G[src]
__global__ __launch_bounds__(256, 2) void gcn_fused(
    const float* __restrict__ F, const int* __restrict__ src,
    const int* __restrict__ dst, const float* __restrict__ W1,
    const float* __restrict__ b1, const float* __restrict__ W2,
    const float* __restrict__ b2, float* __restrict__ H,
    float* __restrict__ aggbuf, float* __restrict__ out,
    unsigned int* __restrict__ bar)
{
    __shared__ unsigned int Wl[KPAD * WROW];   // 52,992 B
    const int tid = threadIdx.x;

    // ---- stage W1 as packed bf16 pairs, zero-padded rows [1433, KPAD) ----
    for (int idx = tid; idx < KPAD * 8; idx += 256) {
        int k = idx >> 3, c = idx & 7;
        unsigned int u = 0u;
        if (k < IN_FEATS) {
            unsigned int lo = f2bf(W1[k * 16 + 2 * c]);
            unsigned int hi = f2bf(W1[k * 16 + 2 * c + 1]);
            u = lo | (hi << 16);
        }
        Wl[k * WROW + c] = u;
    }
    __syncthreads();

    // ---- Phase 1: per-wave 4-row chunks, grid-strided ----
    const int lane = tid & 63;
    const float b1v = b1[lane & 15];
    const int gwave  = blockIdx.x * 4 + (tid >> 6);
    const int nwaves = GRID * 4;

    for (int ch = gwave; ch < N_NODES / 4; ch += nwaves) {
        const int r0 = ch * 4;
        const float* fp = F + (size_t)r0 * IN_FEATS;

        float v[64];
        #pragma unroll
        for (int i = 0; i < 64; ++i) v[i] = 0.f;

        #pragma unroll 2
        for (int i = 0; i < 22; ++i) {          // k < 1408: no bounds check
            const int k = i * 64 + lane;
            const float f0 = fp[k];
            const float f1 = fp[IN_FEATS + k];
            const float f2 = fp[2 * IN_FEATS + k];
            const float f3 = fp[3 * IN_FEATS + k];
            float wv[16];
            #pragma unroll
            for (int c = 0; c < 8; ++c) {
                unsigned int u = Wl[k * WROW + c];
                wv[2 * c]     = __uint_as_float(u << 16);
                wv[2 * c + 1] = __uint_as_float(u & 0xffff0000u);
            }
            #pragma unroll
            for (int j = 0; j < 16; ++j) {
                v[j]      += f0 * wv[j];
                v[16 + j] += f1 * wv[j];
                v[32 + j] += f2 * wv[j];
                v[48 + j] += f3 * wv[j];
            }
        }
        {   // masked tail: k = 1408 + lane
            const int k = 1408 + lane;
            float f0 = 0.f, f1 = 0.f, f2 = 0.f, f3 = 0.f;
            if (k < IN_FEATS) {
                f0 = fp[k];
                f1 = fp[IN_FEATS + k];
                f2 = fp[2 * IN_FEATS + k];
                f3 = fp[3 * IN_FEATS + k];
            }
            float wv[16];
            #pragma unroll
            for (int c = 0; c < 8; ++c) {
                unsigned int u = Wl[k * WROW + c];   // zero-padded rows
                wv[2 * c]     = __uint_as_float(u << 16);
                wv[2 * c + 1] = __uint_as_float(u & 0xffff0000u);
            }
            #pragma unroll
            for (int j = 0; j < 16; ++j) {
                v[j]      += f0 * wv[j];
                v[16 + j] += f1 * wv[j];
                v[32 + j] += f2 * wv[j];
                v[48 + j] += f3 * wv[j];
            }
        }

        // Halving butterfly: lane l ends with v[0] = full sum of idx = l
        #pragma unroll
        for (int d = 5; d >= 0; --d) {
            const int half = 1 << d;
            const bool hi = (lane >> d) & 1;
            #pragma unroll
            for (int t = 0; t < (1 << d); ++t) {
                float sent = hi ? v[t] : v[t + half];
                float recv = __shfl_xor(sent, half, 64);
                float keep = hi ? v[t + half] : v[t];
                v[t] = keep + recv;
            }
        }
        const size_t off = (size_t)r0 * 16 + lane;
        H[off] = v[0];
        aggbuf[off] = v[0] + b1v;
    }

    grid_barrier(bar, GRID);

    // ---- Phase 2: layer-1 edge scatter ----
    const int tglob = blockIdx.x * 256 + tid;
    const int T = GRID * 256;
    for (int i = tglob; i < N_EDGES * 16; i += T) {
        int e = i >> 4, j = i & 15;
        int s = src[e], d = dst[e];
        atomicAdd(&aggbuf[(size_t)d * 16 + j], H[(size_t)s * 16 + j]);
    }

    grid_barrier(bar, 2 * GRID);

    // ---- Phase 3: relu + layer-2 GEMV; G aliases H (dead after P2) ----
    float* G = H;
    for (int n = tglob; n < N_NODES; n += T) {
        const float* a = aggbuf + (size_t)n * 16;
        float x[16];
        #pragma unroll
        for (int k = 0; k < 16; ++k) { float vv = a[k]; x[k] = vv > 0.f ? vv : 0.f; }
        #pragma unroll
        for (int j = 0; j < OUT_F; ++j) {
            float g = 0.f;
            #pragma unroll
            for (int k = 0; k < 16; ++k) g += x[k] * W2[k * OUT_F + j];
            G[(size_t)n * OUT_F + j] = g;
            out[(size_t)n * OUT_F + j] = g + b2[j];
        }
    }

    grid_barrier(bar, 3 * GRID);

    // ---- Phase 4: layer-2 edge scatter ----
    for (int i = tglob; i < N_EDGES * OUT_F; i += T) {
        int e = i / OUT_F, j = i % OUT_F;
        atomicAdd(&out[(size_t)dst[e] * OUT_F + j], G[(size_t)src[e] * OUT_F + j]);
    }
}

extern "C" void kernel_launch(void* const* d_in, const int* in_sizes, int n_in,
                              void* d_out, int out_size, void* d_ws, size_t ws_size,
                              hipStream_t stream)
{
    const float* F   = (const float*)d_in[0];
    const int*   src = (const int*)d_in[1];
    const int*   dst = (const int*)d_in[2];
    const float* W1  = (const float*)d_in[3];
    const float* b1  = (const float*)d_in[4];
    const float* W2  = (const float*)d_in[5];
    const float* b2  = (const float*)d_in[6];
    float* out = (float*)d_out;

    float* H      = (float*)d_ws;                     // 800,000 f32 (G aliases after P2)
    float* aggbuf = H + (size_t)N_NODES * HIDDEN;     // 800,000 f32
    unsigned int* bar = (unsigned int*)(aggbuf + (size_t)N_NODES * HIDDEN);

    hipMemsetAsync(bar, 0, sizeof(unsigned int), stream);

    gcn_fused<<<GRID, 256, 0, stream>>>(F, src, dst, W1, b1, W2, b2,
                                        H, aggbuf, out, bar);
}

// Round 5
// 267.687 us; speedup vs baseline: 1.5734x; 1.5734x over previous
//
#include <hip/hip_runtime.h>
#include <hip/hip_bf16.h>

#define N_NODES  50000
#define N_EDGES  300000
#define IN_FEATS 1433
#define HIDDEN   16
#define OUT_F    7
#define KPAD     1472   // 23*64, zero-padded K extent for W1 in LDS
#define WROW     9      // dwords per W1 row in LDS (stride 9 -> 2-way alias = free)

__device__ __forceinline__ unsigned short f2bf(float f) {
    unsigned int x = __float_as_uint(f);
    unsigned int r = x + 0x7fffu + ((x >> 16) & 1u);   // RNE
    return (unsigned short)(r >> 16);
}

// ---------- CSR build (in-edges, by dst) ----------
__global__ __launch_bounds__(256) void k_hist(const int* __restrict__ dst,
                                              int* __restrict__ counts) {
    int e = blockIdx.x * 256 + threadIdx.x;
    if (e < N_EDGES) atomicAdd(&counts[dst[e]], 1);
}

// Single-block exclusive scan of 50000 counts -> offsets (and cursor copy).
__global__ __launch_bounds__(1024) void k_scan(const int* __restrict__ counts,
                                               int* __restrict__ offsets,
                                               int* __restrict__ cursor) {
    __shared__ int L[1024];
    const int t = threadIdx.x;
    const int base = t * 49;                 // 1024*49 = 50176 >= 50000
    int sum = 0;
    for (int i = 0; i < 49; ++i) {
        int g = base + i;
        if (g < N_NODES) sum += counts[g];
    }
    L[t] = sum;
    __syncthreads();
    for (int s = 1; s < 1024; s <<= 1) {     // Hillis-Steele inclusive scan
        int v = (t >= s) ? L[t - s] : 0;
        __syncthreads();
        L[t] += v;
        __syncthreads();
    }
    int run = L[t] - sum;                    // exclusive base for this chunk
    for (int i = 0; i < 49; ++i) {
        int g = base + i;
        if (g < N_NODES) {
            int c = counts[g];
            offsets[g] = run;
            cursor[g]  = run;
            run += c;
        }
    }
    if (t == 1023) offsets[N_NODES] = L[1023];
}

__global__ __launch_bounds__(256) void k_fill(const int* __restrict__ src,
                                              const int* __restrict__ dst,
                                              int* __restrict__ cursor,
                                              int* __restrict__ csr) {
    int e = blockIdx.x * 256 + threadIdx.x;
    if (e < N_EDGES) {
        int pos = atomicAdd(&cursor[dst[e]], 1);
        csr[pos] = src[e];
    }
}

// ---------- Kernel 1 (unchanged from R2): H = F @ W1; aggbuf = H + b1 ----------
__global__ __launch_bounds__(256) void k1_gemm(
    const float* __restrict__ F, const float* __restrict__ W1,
    const float* __restrict__ b1, float* __restrict__ H,
    float* __restrict__ aggbuf)
{
    __shared__ unsigned int Wl[KPAD * WROW];   // 52,992 B -> 3 blocks/CU
    const int tid = threadIdx.x;

    for (int idx = tid; idx < KPAD * 8; idx += 256) {
        int k = idx >> 3, c = idx & 7;
        unsigned int u = 0u;
        if (k < IN_FEATS) {
            unsigned int lo = f2bf(W1[k * 16 + 2 * c]);
            unsigned int hi = f2bf(W1[k * 16 + 2 * c + 1]);
            u = lo | (hi << 16);
        }
        Wl[k * WROW + c] = u;
    }
    __syncthreads();

    const int lane = tid & 63;
    const float b1v = b1[lane & 15];
    const int gwave  = blockIdx.x * 4 + (tid >> 6);
    const int nwaves = gridDim.x * 4;

    for (int ch = gwave; ch < N_NODES / 4; ch += nwaves) {
        const int r0 = ch * 4;
        const float* fp = F + (size_t)r0 * IN_FEATS;

        float v[64];
        #pragma unroll
        for (int i = 0; i < 64; ++i) v[i] = 0.f;

        #pragma unroll 2
        for (int i = 0; i < 22; ++i) {          // k < 1408: no bounds check
            const int k = i * 64 + lane;
            const float f0 = fp[k];
            const float f1 = fp[IN_FEATS + k];
            const float f2 = fp[2 * IN_FEATS + k];
            const float f3 = fp[3 * IN_FEATS + k];
            float wv[16];
            #pragma unroll
            for (int c = 0; c < 8; ++c) {
                unsigned int u = Wl[k * WROW + c];
                wv[2 * c]     = __uint_as_float(u << 16);
                wv[2 * c + 1] = __uint_as_float(u & 0xffff0000u);
            }
            #pragma unroll
            for (int j = 0; j < 16; ++j) {
                v[j]      += f0 * wv[j];
                v[16 + j] += f1 * wv[j];
                v[32 + j] += f2 * wv[j];
                v[48 + j] += f3 * wv[j];
            }
        }
        {   // masked tail: k = 1408 + lane
            const int k = 1408 + lane;
            float f0 = 0.f, f1 = 0.f, f2 = 0.f, f3 = 0.f;
            if (k < IN_FEATS) {
                f0 = fp[k];
                f1 = fp[IN_FEATS + k];
                f2 = fp[2 * IN_FEATS + k];
                f3 = fp[3 * IN_FEATS + k];
            }
            float wv[16];
            #pragma unroll
            for (int c = 0; c < 8; ++c) {
                unsigned int u = Wl[k * WROW + c];   // zero-padded rows
                wv[2 * c]     = __uint_as_float(u << 16);
                wv[2 * c + 1] = __uint_as_float(u & 0xffff0000u);
            }
            #pragma unroll
            for (int j = 0; j < 16; ++j) {
                v[j]      += f0 * wv[j];
                v[16 + j] += f1 * wv[j];
                v[32 + j] += f2 * wv[j];
                v[48 + j] += f3 * wv[j];
            }
        }

        #pragma unroll
        for (int d = 5; d >= 0; --d) {
            const int half = 1 << d;
            const bool hi = (lane >> d) & 1;
            #pragma unroll
            for (int t = 0; t < (1 << d); ++t) {
                float sent = hi ? v[t] : v[t + half];
                float recv = __shfl_xor(sent, half, 64);
                float keep = hi ? v[t + half] : v[t];
                v[t] = keep + recv;
            }
        }
        const size_t off = (size_t)r0 * 16 + lane;
        H[off] = v[0];
        aggbuf[off] = v[0] + b1v;
    }
}

// ---------- Kernel 2': per-node pull, no atomics ----------
// One wave per node: j = lane&15 (feature), c = lane>>4 (4 edge slots).
__global__ __launch_bounds__(256) void k2_pull(
    const int* __restrict__ offsets, const int* __restrict__ csr,
    const float* __restrict__ H, float* __restrict__ aggbuf)
{
    const int v = blockIdx.x * 4 + (threadIdx.x >> 6);
    if (v >= N_NODES) return;
    const int lane = threadIdx.x & 63;
    const int j = lane & 15, c = lane >> 4;
    const int off = offsets[v], end = offsets[v + 1];
    if (end <= off) return;
    float acc = 0.f;
    for (int base = off; base < end; base += 4) {
        int idx = base + c;
        if (idx < end) {
            int s = csr[idx];
            acc += H[(size_t)s * 16 + j];
        }
    }
    acc += __shfl_xor(acc, 16, 64);
    acc += __shfl_xor(acc, 32, 64);
    if (lane < 16) aggbuf[(size_t)v * 16 + j] += acc;   // owned row, plain RMW
}

// ---------- Kernel 3 (unchanged): relu + layer-2 GEMV ----------
__global__ __launch_bounds__(256) void k3_layer2(
    const float* __restrict__ aggbuf, const float* __restrict__ W2,
    const float* __restrict__ b2, float* __restrict__ G,
    float* __restrict__ out)
{
    int n = blockIdx.x * 256 + threadIdx.x;
    if (n >= N_NODES) return;
    const float* a = aggbuf + (size_t)n * 16;
    float x[16];
    #pragma unroll
    for (int k = 0; k < 16; ++k) { float vv = a[k]; x[k] = vv > 0.f ? vv : 0.f; }
    #pragma unroll
    for (int j = 0; j < OUT_F; ++j) {
        float g = 0.f;
        #pragma unroll
        for (int k = 0; k < 16; ++k) g += x[k] * W2[k * OUT_F + j];
        G[(size_t)n * OUT_F + j] = g;
        out[(size_t)n * OUT_F + j] = g + b2[j];
    }
}

// ---------- Kernel 4': per-node pull, no atomics ----------
// One wave per node: j = lane&7 (feature, j<7 active), c = lane>>3 (8 slots).
__global__ __launch_bounds__(256) void k4_pull(
    const int* __restrict__ offsets, const int* __restrict__ csr,
    const float* __restrict__ G, float* __restrict__ out)
{
    const int v = blockIdx.x * 4 + (threadIdx.x >> 6);
    if (v >= N_NODES) return;
    const int lane = threadIdx.x & 63;
    const int j = lane & 7, c = lane >> 3;
    const int off = offsets[v], end = offsets[v + 1];
    if (end <= off) return;
    float acc = 0.f;
    for (int base = off; base < end; base += 8) {
        int idx = base + c;
        if (idx < end && j < 7) {
            acc += G[(size_t)csr[idx] * 7 + j];
        }
    }
    acc += __shfl_xor(acc, 8, 64);
    acc += __shfl_xor(acc, 16, 64);
    acc += __shfl_xor(acc, 32, 64);
    if (lane < 8 && j < 7) out[(size_t)v * 7 + j] += acc;
}

extern "C" void kernel_launch(void* const* d_in, const int* in_sizes, int n_in,
                              void* d_out, int out_size, void* d_ws, size_t ws_size,
                              hipStream_t stream)
{
    const float* F   = (const float*)d_in[0];
    const int*   src = (const int*)d_in[1];
    const int*   dst = (const int*)d_in[2];
    const float* W1  = (const float*)d_in[3];
    const float* b1  = (const float*)d_in[4];
    const float* W2  = (const float*)d_in[5];
    const float* b2  = (const float*)d_in[6];
    float* out = (float*)d_out;

    float* H      = (float*)d_ws;                       // 800,000 f32
    float* aggbuf = H + (size_t)N_NODES * HIDDEN;       // 800,000 f32
    float* G      = H;                                  // reuse H after k2' (dead)
    int* counts   = (int*)(aggbuf + (size_t)N_NODES * HIDDEN);  // 50,000
    int* offsets  = counts + N_NODES;                   // 50,001
    int* cursor   = offsets + N_NODES + 1;              // 50,000
    int* csr      = cursor + N_NODES;                   // 300,000

    hipMemsetAsync(counts, 0, N_NODES * sizeof(int), stream);
    k_hist<<<(N_EDGES + 255) / 256, 256, 0, stream>>>(dst, counts);
    k_scan<<<1, 1024, 0, stream>>>(counts, offsets, cursor);
    k_fill<<<(N_EDGES + 255) / 256, 256, 0, stream>>>(src, dst, cursor, csr);

    k1_gemm<<<768, 256, 0, stream>>>(F, W1, b1, H, aggbuf);
    k2_pull<<<(N_NODES + 3) / 4, 256, 0, stream>>>(offsets, csr, H, aggbuf);
    k3_layer2<<<(N_NODES + 255) / 256, 256, 0, stream>>>(aggbuf, W2, b2, G, out);
    k4_pull<<<(N_NODES + 3) / 4, 256, 0, stream>>>(offsets, csr, G, out);
}

// Round 6
// 116.789 us; speedup vs baseline: 3.6063x; 2.2921x over previous
//
#include <hip/hip_runtime.h>
#include <hip/hip_fp16.h>

#define N_NODES  50000
#define N_EDGES  300000
#define IN_FEATS 1433
#define HIDDEN   16
#define OUT_F    7
#define KPAD     1472   // 23*64, zero-padded K extent for W1 in LDS
#define WROW     9      // dwords per W1 row in LDS (stride 9 -> 2-way alias = free)

// ---------- Kernel 1: H = F @ W1 (fp16 W in LDS); outputs fp16 H and aggbuf=H+b1 ----------
__global__ __launch_bounds__(256) void k1_gemm(
    const float* __restrict__ F, const float* __restrict__ W1,
    const float* __restrict__ b1, __half* __restrict__ H,
    __half* __restrict__ aggbuf)
{
    __shared__ unsigned int Wl[KPAD * WROW];   // 52,992 B -> 3 blocks/CU
    const int tid = threadIdx.x;

    // Stage W1 as packed fp16 pairs (RNE), zero-padded rows [1433, KPAD)
    for (int idx = tid; idx < KPAD * 8; idx += 256) {
        int k = idx >> 3, c = idx & 7;
        unsigned int u = 0u;
        if (k < IN_FEATS) {
            __half2 h2 = __floats2half2_rn(W1[k * 16 + 2 * c], W1[k * 16 + 2 * c + 1]);
            u = *reinterpret_cast<unsigned int*>(&h2);
        }
        Wl[k * WROW + c] = u;
    }
    __syncthreads();

    const int lane = tid & 63;
    const float b1v = b1[lane & 15];
    const int gwave  = blockIdx.x * 4 + (tid >> 6);
    const int nwaves = gridDim.x * 4;

    for (int ch = gwave; ch < N_NODES / 4; ch += nwaves) {
        const int r0 = ch * 4;
        const float* fp = F + (size_t)r0 * IN_FEATS;

        float v[64];                                    // acc[idx = r*16 + j]
        #pragma unroll
        for (int i = 0; i < 64; ++i) v[i] = 0.f;

        #pragma unroll 2
        for (int i = 0; i < 22; ++i) {          // k < 1408: no bounds check
            const int k = i * 64 + lane;
            const float f0 = fp[k];
            const float f1 = fp[IN_FEATS + k];
            const float f2 = fp[2 * IN_FEATS + k];
            const float f3 = fp[3 * IN_FEATS + k];
            float wv[16];
            #pragma unroll
            for (int c = 0; c < 8; ++c) {
                unsigned int u = Wl[k * WROW + c];
                __half2 h2 = *reinterpret_cast<__half2*>(&u);
                float2 f = __half22float2(h2);
                wv[2 * c]     = f.x;
                wv[2 * c + 1] = f.y;
            }
            #pragma unroll
            for (int j = 0; j < 16; ++j) {
                v[j]      += f0 * wv[j];
                v[16 + j] += f1 * wv[j];
                v[32 + j] += f2 * wv[j];
                v[48 + j] += f3 * wv[j];
            }
        }
        {   // masked tail: k = 1408 + lane
            const int k = 1408 + lane;
            float f0 = 0.f, f1 = 0.f, f2 = 0.f, f3 = 0.f;
            if (k < IN_FEATS) {
                f0 = fp[k];
                f1 = fp[IN_FEATS + k];
                f2 = fp[2 * IN_FEATS + k];
                f3 = fp[3 * IN_FEATS + k];
            }
            float wv[16];
            #pragma unroll
            for (int c = 0; c < 8; ++c) {
                unsigned int u = Wl[k * WROW + c];   // zero-padded rows
                __half2 h2 = *reinterpret_cast<__half2*>(&u);
                float2 f = __half22float2(h2);
                wv[2 * c]     = f.x;
                wv[2 * c + 1] = f.y;
            }
            #pragma unroll
            for (int j = 0; j < 16; ++j) {
                v[j]      += f0 * wv[j];
                v[16 + j] += f1 * wv[j];
                v[32 + j] += f2 * wv[j];
                v[48 + j] += f3 * wv[j];
            }
        }

        // Halving butterfly: lane l ends with v[0] = full K-sum of idx = l
        #pragma unroll
        for (int d = 5; d >= 0; --d) {
            const int half = 1 << d;
            const bool hi = (lane >> d) & 1;
            #pragma unroll
            for (int t = 0; t < (1 << d); ++t) {
                float sent = hi ? v[t] : v[t + half];
                float recv = __shfl_xor(sent, half, 64);
                float keep = hi ? v[t + half] : v[t];
                v[t] = keep + recv;
            }
        }
        const size_t off = (size_t)r0 * 16 + lane;
        H[off]      = __float2half(v[0]);
        aggbuf[off] = __float2half(v[0] + b1v);
    }
}

// ---------- Kernel 2: aggbuf[dst] += H[src], packed-fp16 atomics (8 thr/edge) ----------
__global__ __launch_bounds__(256) void k2_scatter1(
    const int* __restrict__ src, const int* __restrict__ dst,
    const __half2* __restrict__ H2, __half2* __restrict__ agg2)
{
    int t = blockIdx.x * 256 + threadIdx.x;     // grid sized exactly N_EDGES*8
    int e = t >> 3, p = t & 7;
    int s = src[e], d = dst[e];
    __half2 val = H2[(size_t)s * 8 + p];
    unsafeAtomicAdd(&agg2[(size_t)d * 8 + p], val);   // global_atomic_pk_add_f16
}

// ---------- Kernel 3: x = relu(aggbuf fp16); G = x @ W2; out = G + b2 ----------
__global__ __launch_bounds__(256) void k3_layer2(
    const __half2* __restrict__ agg2, const float* __restrict__ W2,
    const float* __restrict__ b2, float* __restrict__ G,
    float* __restrict__ out)
{
    int n = blockIdx.x * 256 + threadIdx.x;
    if (n >= N_NODES) return;
    float x[16];
    #pragma unroll
    for (int p = 0; p < 8; ++p) {
        float2 f = __half22float2(agg2[(size_t)n * 8 + p]);
        x[2 * p]     = f.x > 0.f ? f.x : 0.f;
        x[2 * p + 1] = f.y > 0.f ? f.y : 0.f;
    }
    #pragma unroll
    for (int j = 0; j < OUT_F; ++j) {
        float g = 0.f;
        #pragma unroll
        for (int k = 0; k < 16; ++k) g += x[k] * W2[k * OUT_F + j];
        G[(size_t)n * OUT_F + j] = g;
        out[(size_t)n * OUT_F + j] = g + b2[j];
    }
}

// ---------- Kernel 4: out[dst] += G[src], f32 atomics (unchanged) ----------
__global__ __launch_bounds__(256) void k4_scatter2(
    const int* __restrict__ src, const int* __restrict__ dst,
    const float* __restrict__ G, float* __restrict__ out)
{
    int t = blockIdx.x * 256 + threadIdx.x;
    int e = t / OUT_F, j = t % OUT_F;
    if (e < N_EDGES) {
        atomicAdd(&out[(size_t)dst[e] * OUT_F + j], G[(size_t)src[e] * OUT_F + j]);
    }
}

extern "C" void kernel_launch(void* const* d_in, const int* in_sizes, int n_in,
                              void* d_out, int out_size, void* d_ws, size_t ws_size,
                              hipStream_t stream)
{
    const float* F   = (const float*)d_in[0];
    const int*   src = (const int*)d_in[1];
    const int*   dst = (const int*)d_in[2];
    const float* W1  = (const float*)d_in[3];
    const float* b1  = (const float*)d_in[4];
    const float* W2  = (const float*)d_in[5];
    const float* b2  = (const float*)d_in[6];
    float* out = (float*)d_out;

    __half* H      = (__half*)d_ws;                         // 800,000 fp16 (1.6 MB)
    __half* aggbuf = H + (size_t)N_NODES * HIDDEN;          // 800,000 fp16 (1.6 MB)
    float*  G      = (float*)(aggbuf + (size_t)N_NODES * HIDDEN);  // 350,000 f32

    k1_gemm<<<768, 256, 0, stream>>>(F, W1, b1, H, aggbuf);
    k2_scatter1<<<(N_EDGES * 8) / 256, 256, 0, stream>>>(src, dst,
        (const __half2*)H, (__half2*)aggbuf);
    k3_layer2<<<(N_NODES + 255) / 256, 256, 0, stream>>>((const __half2*)aggbuf,
        W2, b2, G, out);
    k4_scatter2<<<(N_EDGES * OUT_F + 255) / 256, 256, 0, stream>>>(src, dst, G, out);
}